// Round 7
// baseline (115.637 us; speedup 1.0000x reference)
//
#include <hip/hip_runtime.h>

// Problem constants
#define BATCH 16384
#define KEYD  64
#define DDIM  128
#define UDIM  128
#define MODES 32

typedef __attribute__((ext_vector_type(8))) short bf16x8;   // 8 bf16 in 4 VGPRs
typedef __attribute__((ext_vector_type(4))) float f32x4;

__device__ __forceinline__ unsigned short f2bf(float f) {
  unsigned u = __float_as_uint(f);
  unsigned r = (u + 0x7FFFu + ((u >> 16) & 1u)) >> 16;  // RNE bf16
  return (unsigned short)r;
}

__device__ __forceinline__ void gld_lds16(const void* g, void* l) {
  __builtin_amdgcn_global_load_lds(
      (const __attribute__((address_space(1))) unsigned int*)g,
      (__attribute__((address_space(3))) unsigned int*)l, 16, 0, 0);
}

// ---------------------------------------------------------------------------
// Fused prep — proven version; also writes simT[mode][row] (transposed sim)
// so the GEMM can broadcast-load per-mode scales from global.
// ---------------------------------------------------------------------------
__global__ __launch_bounds__(256) void prep_all(
    const float* __restrict__ key, const float* __restrict__ x,
    const float* __restrict__ sens, const float* __restrict__ keys_map,
    const float* __restrict__ kernels, const float* __restrict__ biases,
    float* __restrict__ sim, float* __restrict__ simT,
    unsigned short* __restrict__ x16,
    unsigned short* __restrict__ kb16, unsigned short* __restrict__ bb16) {
  const int t = threadIdx.x;
  const int bid = blockIdx.x;

  if (bid < BATCH / 32) {
    __shared__ float kr[32][KEYD];   // 32 key rows, 8KB
    __shared__ float sims[32][33];   // [mode][local row], +1 pad
    *(float4*)(&kr[0][0] + t * 4) =
        *(const float4*)(key + (long)bid * 32 * KEYD + t * 4);
    *(float4*)(&kr[0][0] + 1024 + t * 4) =
        *(const float4*)(key + (long)bid * 32 * KEYD + 1024 + t * 4);

    const int lane = t & 63, wave = t >> 6;
    const int m = lane & 31, h = lane >> 5;
    float kreg[32];  // this lane's half of mode m's key row
    {
      const float* kmp = keys_map + m * KEYD + h * 32;
      #pragma unroll
      for (int j = 0; j < 32; j += 4) {
        const float4 v = *(const float4*)(kmp + j);
        kreg[j] = v.x; kreg[j + 1] = v.y; kreg[j + 2] = v.z; kreg[j + 3] = v.w;
      }
    }
    const float sv = sens[m];
    __syncthreads();

    #pragma unroll
    for (int rr = 0; rr < 8; ++rr) {
      const int rl = wave * 8 + rr;
      const long row = (long)bid * 32 + rl;

      float d2h = 0.f;
      #pragma unroll
      for (int j = 0; j < 32; j += 2) {
        const float2 kv = *(const float2*)(&kr[rl][h * 32 + j]);
        float a = kv.x - kreg[j], b = kv.y - kreg[j + 1];
        d2h += a * a + b * b;
      }
      float d2 = d2h + __shfl_xor(d2h, 32, 64);
      float logit = sv / (sqrtf(d2) + 1.0f);
      float mx = logit;
      #pragma unroll
      for (int off = 16; off > 0; off >>= 1) mx = fmaxf(mx, __shfl_xor(mx, off, 64));
      float e = __expf(logit - mx);
      float s = e;
      #pragma unroll
      for (int off = 16; off > 0; off >>= 1) s += __shfl_xor(s, off, 64);
      if (h == 0) {
        const float p = e / s;
        sim[row * MODES + m] = p;
        sims[m][rl] = p;
      }

      const float2 xv = *(const float2*)(x + row * DDIM + lane * 2);
      ushort2 o; o.x = f2bf(xv.x); o.y = f2bf(xv.y);
      *(ushort2*)(x16 + row * DDIM + lane * 2) = o;
    }

    __syncthreads();
    // coalesced simT write: thread t -> mode t>>3, rows (t&7)*4 .. +3
    {
      const int m2 = t >> 3, r0 = (t & 7) * 4;
      float4 v;
      v.x = sims[m2][r0 + 0]; v.y = sims[m2][r0 + 1];
      v.z = sims[m2][r0 + 2]; v.w = sims[m2][r0 + 3];
      *(float4*)(simT + (long)m2 * BATCH + (long)bid * 32 + r0) = v;
    }
  } else {
    int tt = (bid - BATCH / 32) * 256 + t;
    if (tt < MODES * 16 * UDIM) {
      int u = tt & 127, kb = (tt >> 7) & 15, m = tt >> 11;
      const float* src = kernels + (long)((m * 16 + kb) * 8) * UDIM + u;
      ushort4 lo, hi;
      lo.x = f2bf(src[0 * UDIM]); lo.y = f2bf(src[1 * UDIM]);
      lo.z = f2bf(src[2 * UDIM]); lo.w = f2bf(src[3 * UDIM]);
      hi.x = f2bf(src[4 * UDIM]); hi.y = f2bf(src[5 * UDIM]);
      hi.z = f2bf(src[6 * UDIM]); hi.w = f2bf(src[7 * UDIM]);
      *(ushort4*)(kb16 + (long)tt * 8) = lo;
      *(ushort4*)(kb16 + (long)tt * 8 + 4) = hi;
    } else {
      int tb = tt - MODES * 16 * UDIM;
      int u = tb & 127, kb = tb >> 7;
      const float* src = biases + kb * 8 * UDIM + u;
      ushort4 lo, hi;
      lo.x = f2bf(src[0 * UDIM]); lo.y = f2bf(src[1 * UDIM]);
      lo.z = f2bf(src[2 * UDIM]); lo.w = f2bf(src[3 * UDIM]);
      hi.x = f2bf(src[4 * UDIM]); hi.y = f2bf(src[5 * UDIM]);
      hi.z = f2bf(src[6 * UDIM]); hi.w = f2bf(src[7 * UDIM]);
      *(ushort4*)(bb16 + (long)tb * 8) = lo;
      *(ushort4*)(bb16 + (long)tb * 8 + 4) = hi;
    }
  }
}

// ---------------------------------------------------------------------------
// Strip-resident GEMM v2: same once-only B staging (chip-wide kb16 volume
// 32 MB, FETCH ~8 MB verified in R6), but 8 waves / 512 threads per block
// -> 2 waves/SIMD for latency hiding (R6 ran 1 wave/SIMD and was pure
// latency-bound: MfmaUtil 14%, BW 0.4 TB/s).
//   grid 256 = 8 col-strips x 32 row-groups. Block = 16 cols x 512 rows;
//   wave = 64 rows (aF 64 VGPR). LDS: one 64 KB half-buffer of B (16 modes);
//   half 1 register-prefetched (8 x bf16x8/thread) during half-0 compute,
//   ds_written after barrier 2 (T14). 3 barriers total.
//   Per mode: 4 sv broadcast loads (even/odd pipelined) + 4 ds_read_b128
//   + 16 MFMA as 8 independent depth-2 chains.
// ---------------------------------------------------------------------------
__global__ __launch_bounds__(512, 2) void gemm_strip(
    const unsigned short* __restrict__ x16, const unsigned short* __restrict__ kb16,
    const unsigned short* __restrict__ bb16, const float* __restrict__ sim,
    const float* __restrict__ simT, float* __restrict__ out) {
  // [chunk c = m_local*16 + kb][col 16][8 shorts] : 64 KB (16 modes)
  __shared__ alignas(16) unsigned short bshB[256 * 16 * 8];

  const int t = threadIdx.x;
  const int lane = t & 63, w = t >> 6;
  const int q = lane >> 4, l16 = lane & 15;
  const int bid = blockIdx.x;
  const int group = bid & 31, strip = bid >> 5;
  const long bm = (long)group * 512;
  const int wrow = w * 64;

  // ---- issue stage of half 0 (modes 0..15): 64 x 1KB gld_lds, 8/wave ----
  // instr j = i*8 + w covers chunks 4j..4j+3; lane supplies 16B of chunk
  // 4j + (lane>>4), col (lane&15). LDS dest = 1024*j + lane*16 (linear).
  #pragma unroll
  for (int i = 0; i < 8; ++i) {
    const int j = i * 8 + w;
    const int c = 4 * j + (lane >> 4);
    const int m_l = c >> 4, kb = c & 15;
    gld_lds16(kb16 + ((long)m_l * 16 + kb) * (UDIM * 8) + (strip * 16 + (lane & 15)) * 8,
              &bshB[(c * 16 + (lane & 15)) * 8]);
  }

  // ---- A fragments: 64 rows x K=128 per wave, in registers (64 VGPR) ----
  bf16x8 aF[4][4];
  #pragma unroll
  for (int rt = 0; rt < 4; ++rt)
    #pragma unroll
    for (int ks = 0; ks < 4; ++ks)
      aF[rt][ks] = *(const bf16x8*)(x16 + (bm + wrow + rt * 16 + l16) * DDIM + ks * 32 + q * 8);

  __syncthreads();  // barrier 1: half 0 staged (drain), aF in regs

  // ---- prefetch half 1 (modes 16..31) into registers (32 VGPR) ----
  bf16x8 pf[8];
  #pragma unroll
  for (int i = 0; i < 8; ++i) {
    const int j = i * 8 + w;
    const int c = 4 * j + (lane >> 4);
    const int m_l = c >> 4, kb = c & 15;
    pf[i] = *(const bf16x8*)(kb16 + ((long)(16 + m_l) * 16 + kb) * (UDIM * 8)
                             + (strip * 16 + (lane & 15)) * 8);
  }

  f32x4 acc[4] = {};
  const float* svbase = simT + bm + wrow + q * 4;

#define LOAD_SV(dst, mg)                                                        \
  { _Pragma("unroll")                                                           \
    for (int rt = 0; rt < 4; ++rt)                                              \
      dst[rt] = *(const f32x4*)(svbase + (long)(mg) * BATCH + rt * 16); }

  // 16 MFMA as 4 rt x 2 independent depth-2 chains (shorter dep latency)
#define COMPUTE_MODE(ml, SV)                                                    \
  { bf16x8 bF[4];                                                               \
    _Pragma("unroll")                                                           \
    for (int ks = 0; ks < 4; ++ks)                                              \
      bF[ks] = *(const bf16x8*)&bshB[(((ml) * 16 + ks * 4 + q) * 16 + l16) * 8];\
    _Pragma("unroll")                                                           \
    for (int rt = 0; rt < 4; ++rt) {                                            \
      f32x4 t0 = {}, t1 = {};                                                   \
      t0 = __builtin_amdgcn_mfma_f32_16x16x32_bf16(aF[rt][0], bF[0], t0, 0, 0, 0); \
      t1 = __builtin_amdgcn_mfma_f32_16x16x32_bf16(aF[rt][1], bF[1], t1, 0, 0, 0); \
      t0 = __builtin_amdgcn_mfma_f32_16x16x32_bf16(aF[rt][2], bF[2], t0, 0, 0, 0); \
      t1 = __builtin_amdgcn_mfma_f32_16x16x32_bf16(aF[rt][3], bF[3], t1, 0, 0, 0); \
      acc[rt] += SV[rt] * (t0 + t1);                                            \
    } }

  for (int h = 0; h < 2; ++h) {
    if (h == 1) {
      __syncthreads();  // barrier 2: all waves done reading half 0
      #pragma unroll
      for (int i = 0; i < 8; ++i) {
        const int j = i * 8 + w;
        const int c = 4 * j + (lane >> 4);
        *(bf16x8*)&bshB[(c * 16 + (lane & 15)) * 8] = pf[i];
      }
      __syncthreads();  // barrier 3: half 1 visible
    }
    f32x4 svA[4], svB[4];
    LOAD_SV(svA, h * 16);
    #pragma unroll 2
    for (int ml = 0; ml < 16; ml += 2) {
      LOAD_SV(svB, h * 16 + ml + 1);
      COMPUTE_MODE(ml, svA);
      if (ml + 2 < 16) LOAD_SV(svA, h * 16 + ml + 2);
      COMPUTE_MODE(ml + 1, svB);
    }
  }
#undef LOAD_SV
#undef COMPUTE_MODE

  // ---- bias: one K=32 MFMA round (A = sim rows bf16, B = biases) ----
  {
    const bf16x8 bb = *(const bf16x8*)(bb16 + ((long)q * UDIM + strip * 16 + l16) * 8);
    #pragma unroll
    for (int rt = 0; rt < 4; ++rt) {
      const float* sp = sim + (bm + wrow + rt * 16 + l16) * MODES + q * 8;
      const float4 sv0 = *(const float4*)(sp);
      const float4 sv1 = *(const float4*)(sp + 4);
      bf16x8 sF;
      sF[0] = (short)f2bf(sv0.x); sF[1] = (short)f2bf(sv0.y);
      sF[2] = (short)f2bf(sv0.z); sF[3] = (short)f2bf(sv0.w);
      sF[4] = (short)f2bf(sv1.x); sF[5] = (short)f2bf(sv1.y);
      sF[6] = (short)f2bf(sv1.z); sF[7] = (short)f2bf(sv1.w);
      acc[rt] = __builtin_amdgcn_mfma_f32_16x16x32_bf16(sF, bb, acc[rt], 0, 0, 0);
    }
  }

  // ---- epilogue: direct store, 1/MODES folded in ----
  #pragma unroll
  for (int rt = 0; rt < 4; ++rt) {
    const long row = bm + wrow + rt * 16 + q * 4;
    #pragma unroll
    for (int r = 0; r < 4; ++r)
      out[(row + r) * UDIM + strip * 16 + l16] = acc[rt][r] * (1.0f / MODES);
  }
}

extern "C" void kernel_launch(void* const* d_in, const int* in_sizes, int n_in,
                              void* d_out, int out_size, void* d_ws, size_t ws_size,
                              hipStream_t stream) {
  const float* key      = (const float*)d_in[0];
  const float* x        = (const float*)d_in[1];
  const float* sens     = (const float*)d_in[2];
  const float* keys_map = (const float*)d_in[3];
  const float* kernels  = (const float*)d_in[4];
  const float* biases   = (const float*)d_in[5];
  float* out = (float*)d_out;

  char* ws = (char*)d_ws;
  float*          sim  = (float*)ws;                          // 2 MB
  unsigned short* x16  = (unsigned short*)(ws + (2u << 20));  // 4 MB
  unsigned short* kb16 = (unsigned short*)(ws + (6u << 20));  // 1 MB
  unsigned short* bb16 = (unsigned short*)(ws + (7u << 20));  // 8 KB
  float*          simT = (float*)(ws + (8u << 20));           // 2 MB

  prep_all<<<BATCH / 32 + 258, 256, 0, stream>>>(
      key, x, sens, keys_map, kernels, biases, sim, simT, x16, kb16, bb16);
  gemm_strip<<<dim3(256), 512, 0, stream>>>(x16, kb16, bb16, sim, simT, out);
}

// Round 8
// 104.824 us; speedup vs baseline: 1.1032x; 1.1032x over previous
//
#include <hip/hip_runtime.h>

// Problem constants
#define BATCH 16384
#define KEYD  64
#define DDIM  128
#define UDIM  128
#define MODES 32

typedef __attribute__((ext_vector_type(8))) short bf16x8;   // 8 bf16 in 4 VGPRs
typedef __attribute__((ext_vector_type(4))) float f32x4;

__device__ __forceinline__ unsigned short f2bf(float f) {
  unsigned u = __float_as_uint(f);
  unsigned r = (u + 0x7FFFu + ((u >> 16) & 1u)) >> 16;  // RNE bf16
  return (unsigned short)r;
}

__device__ __forceinline__ void gld_lds16(const void* g, void* l) {
  __builtin_amdgcn_global_load_lds(
      (const __attribute__((address_space(1))) unsigned int*)g,
      (__attribute__((address_space(3))) unsigned int*)l, 16, 0, 0);
}

// ---------------------------------------------------------------------------
// Prep: softmax (sim + simT) and kernels/biases bf16 cast. x is NO LONGER
// touched here — the GEMM reads x f32 directly and converts in-register
// (same RNE f2bf -> bit-identical output), saving 12 MB of prep traffic.
//  blocks [0,512): sim softmax, 32 rows/block.
//  blocks [512,770): cast kernels+biases to bf16 in MFMA-B fragment layout
//    kb16[m][kblk][u][j] = kernels[m][kblk*8+j][u] -> every B-fragment is a
//    contiguous 16B chunk (global_load_lds width-16 friendly).
// ---------------------------------------------------------------------------
__global__ __launch_bounds__(256) void prep_all(
    const float* __restrict__ key, const float* __restrict__ sens,
    const float* __restrict__ keys_map, const float* __restrict__ kernels,
    const float* __restrict__ biases,
    float* __restrict__ sim, float* __restrict__ simT,
    unsigned short* __restrict__ kb16, unsigned short* __restrict__ bb16) {
  const int t = threadIdx.x;
  const int bid = blockIdx.x;

  if (bid < BATCH / 32) {
    __shared__ float kr[32][KEYD];   // 32 key rows, 8KB
    __shared__ float sims[32][33];   // [mode][local row], +1 pad
    *(float4*)(&kr[0][0] + t * 4) =
        *(const float4*)(key + (long)bid * 32 * KEYD + t * 4);
    *(float4*)(&kr[0][0] + 1024 + t * 4) =
        *(const float4*)(key + (long)bid * 32 * KEYD + 1024 + t * 4);

    const int lane = t & 63, wave = t >> 6;
    const int m = lane & 31, h = lane >> 5;
    float kreg[32];  // this lane's half of mode m's key row
    {
      const float* kmp = keys_map + m * KEYD + h * 32;
      #pragma unroll
      for (int j = 0; j < 32; j += 4) {
        const float4 v = *(const float4*)(kmp + j);
        kreg[j] = v.x; kreg[j + 1] = v.y; kreg[j + 2] = v.z; kreg[j + 3] = v.w;
      }
    }
    const float sv = sens[m];
    __syncthreads();

    #pragma unroll
    for (int rr = 0; rr < 8; ++rr) {
      const int rl = wave * 8 + rr;
      const long row = (long)bid * 32 + rl;

      float d2h = 0.f;
      #pragma unroll
      for (int j = 0; j < 32; j += 2) {
        const float2 kv = *(const float2*)(&kr[rl][h * 32 + j]);
        float a = kv.x - kreg[j], b = kv.y - kreg[j + 1];
        d2h += a * a + b * b;
      }
      float d2 = d2h + __shfl_xor(d2h, 32, 64);
      float logit = sv / (sqrtf(d2) + 1.0f);
      float mx = logit;
      #pragma unroll
      for (int off = 16; off > 0; off >>= 1) mx = fmaxf(mx, __shfl_xor(mx, off, 64));
      float e = __expf(logit - mx);
      float s = e;
      #pragma unroll
      for (int off = 16; off > 0; off >>= 1) s += __shfl_xor(s, off, 64);
      if (h == 0) {
        const float p = e / s;
        sim[row * MODES + m] = p;
        sims[m][rl] = p;
      }
    }

    __syncthreads();
    // coalesced simT write: thread t -> mode t>>3, rows (t&7)*4 .. +3
    {
      const int m2 = t >> 3, r0 = (t & 7) * 4;
      float4 v;
      v.x = sims[m2][r0 + 0]; v.y = sims[m2][r0 + 1];
      v.z = sims[m2][r0 + 2]; v.w = sims[m2][r0 + 3];
      *(float4*)(simT + (long)m2 * BATCH + (long)bid * 32 + r0) = v;
    }
  } else {
    int tt = (bid - BATCH / 32) * 256 + t;
    if (tt < MODES * 16 * UDIM) {
      int u = tt & 127, kb = (tt >> 7) & 15, m = tt >> 11;
      const float* src = kernels + (long)((m * 16 + kb) * 8) * UDIM + u;
      ushort4 lo, hi;
      lo.x = f2bf(src[0 * UDIM]); lo.y = f2bf(src[1 * UDIM]);
      lo.z = f2bf(src[2 * UDIM]); lo.w = f2bf(src[3 * UDIM]);
      hi.x = f2bf(src[4 * UDIM]); hi.y = f2bf(src[5 * UDIM]);
      hi.z = f2bf(src[6 * UDIM]); hi.w = f2bf(src[7 * UDIM]);
      *(ushort4*)(kb16 + (long)tt * 8) = lo;
      *(ushort4*)(kb16 + (long)tt * 8 + 4) = hi;
    } else {
      int tb = tt - MODES * 16 * UDIM;
      int u = tb & 127, kb = tb >> 7;
      const float* src = biases + kb * 8 * UDIM + u;
      ushort4 lo, hi;
      lo.x = f2bf(src[0 * UDIM]); lo.y = f2bf(src[1 * UDIM]);
      lo.z = f2bf(src[2 * UDIM]); lo.w = f2bf(src[3 * UDIM]);
      hi.x = f2bf(src[4 * UDIM]); hi.y = f2bf(src[5 * UDIM]);
      hi.z = f2bf(src[6 * UDIM]); hi.w = f2bf(src[7 * UDIM]);
      *(ushort4*)(bb16 + (long)tb * 8) = lo;
      *(ushort4*)(bb16 + (long)tb * 8 + 4) = hi;
    }
  }
}

// ---------------------------------------------------------------------------
// Strip-resident GEMM v3: once-only B staging (FETCH ~8 MB verified R6),
// 8 waves / 512 thr (2 waves/SIMD, R7), PLUS register double-buffering of
// BOTH the B fragments (bFA/bFB) and the sim scales (svA/svB): mode ml+1's
// 4 ds_read_b128 and 4 sv loads issue BEFORE mode ml's 16-MFMA block
// (~310 cyc/wave), so the ~120 cyc LDS latency never sits on the critical
// path. A is read as f32 and converted in-register (RNE f2bf, identical
// numerics) — x16 eliminated.
//   grid 256 = 8 col-strips x 32 row-groups. Block = 16 cols x 512 rows;
//   wave = 64 rows. LDS: one 64 KB half (16 modes); half 1 register-
//   prefetched during half-0 compute, ds_written after barrier 2 (T14).
//   3 barriers total. MFMA issue floor: 19.9k cyc/CU ~= 8.3 us.
// ---------------------------------------------------------------------------
__global__ __launch_bounds__(512, 2) void gemm_strip(
    const float* __restrict__ x, const unsigned short* __restrict__ kb16,
    const unsigned short* __restrict__ bb16, const float* __restrict__ sim,
    const float* __restrict__ simT, float* __restrict__ out) {
  // [chunk c = m_local*16 + kb][col 16][8 shorts] : 64 KB (16 modes)
  __shared__ alignas(16) unsigned short bshB[256 * 16 * 8];

  const int t = threadIdx.x;
  const int lane = t & 63, w = t >> 6;
  const int q = lane >> 4, l16 = lane & 15;
  const int bid = blockIdx.x;
  const int group = bid & 31, strip = bid >> 5;
  const long bm = (long)group * 512;
  const int wrow = w * 64;

  // ---- issue stage of half 0 (modes 0..15): 64 x 1KB gld_lds, 8/wave ----
  #pragma unroll
  for (int i = 0; i < 8; ++i) {
    const int j = i * 8 + w;
    const int c = 4 * j + (lane >> 4);
    const int m_l = c >> 4, kb = c & 15;
    gld_lds16(kb16 + ((long)m_l * 16 + kb) * (UDIM * 8) + (strip * 16 + (lane & 15)) * 8,
              &bshB[(c * 16 + (lane & 15)) * 8]);
  }

  // ---- A fragments: 64 rows x K=128 per wave; f32 load + in-reg bf16 ----
  bf16x8 aF[4][4];
  #pragma unroll
  for (int rt = 0; rt < 4; ++rt)
    #pragma unroll
    for (int ks = 0; ks < 4; ++ks) {
      const float* xp = x + (bm + wrow + rt * 16 + l16) * DDIM + ks * 32 + q * 8;
      const float4 a0 = *(const float4*)(xp);
      const float4 a1 = *(const float4*)(xp + 4);
      bf16x8 f;
      f[0] = (short)f2bf(a0.x); f[1] = (short)f2bf(a0.y);
      f[2] = (short)f2bf(a0.z); f[3] = (short)f2bf(a0.w);
      f[4] = (short)f2bf(a1.x); f[5] = (short)f2bf(a1.y);
      f[6] = (short)f2bf(a1.z); f[7] = (short)f2bf(a1.w);
      aF[rt][ks] = f;
    }

  __syncthreads();  // barrier 1: half 0 staged (drain), aF in regs

  // ---- prefetch half 1 (modes 16..31) into registers (32 VGPR) ----
  bf16x8 pf[8];
  #pragma unroll
  for (int i = 0; i < 8; ++i) {
    const int j = i * 8 + w;
    const int c = 4 * j + (lane >> 4);
    const int m_l = c >> 4, kb = c & 15;
    pf[i] = *(const bf16x8*)(kb16 + ((long)(16 + m_l) * 16 + kb) * (UDIM * 8)
                             + (strip * 16 + (lane & 15)) * 8);
  }

  f32x4 acc[4] = {};
  const float* svbase = simT + bm + wrow + q * 4;

#define LOAD_SV(dst, mg)                                                        \
  { _Pragma("unroll")                                                           \
    for (int rt = 0; rt < 4; ++rt)                                              \
      dst[rt] = *(const f32x4*)(svbase + (long)(mg) * BATCH + rt * 16); }

#define LOAD_BF(dst, ml)                                                        \
  { _Pragma("unroll")                                                           \
    for (int ks = 0; ks < 4; ++ks)                                              \
      dst[ks] = *(const bf16x8*)&bshB[(((ml) * 16 + ks * 4 + q) * 16 + l16) * 8]; }

  // 16 MFMA as 4 rt x 2 independent depth-2 chains
#define COMPUTE_MODE(BF, SV)                                                    \
  { _Pragma("unroll")                                                           \
    for (int rt = 0; rt < 4; ++rt) {                                            \
      f32x4 t0 = {}, t1 = {};                                                   \
      t0 = __builtin_amdgcn_mfma_f32_16x16x32_bf16(aF[rt][0], BF[0], t0, 0, 0, 0); \
      t1 = __builtin_amdgcn_mfma_f32_16x16x32_bf16(aF[rt][1], BF[1], t1, 0, 0, 0); \
      t0 = __builtin_amdgcn_mfma_f32_16x16x32_bf16(aF[rt][2], BF[2], t0, 0, 0, 0); \
      t1 = __builtin_amdgcn_mfma_f32_16x16x32_bf16(aF[rt][3], BF[3], t1, 0, 0, 0); \
      acc[rt] += SV[rt] * (t0 + t1);                                            \
    } }

  for (int h = 0; h < 2; ++h) {
    if (h == 1) {
      __syncthreads();  // barrier 2: all waves done reading half 0
      #pragma unroll
      for (int i = 0; i < 8; ++i) {
        const int j = i * 8 + w;
        const int c = 4 * j + (lane >> 4);
        *(bf16x8*)&bshB[(c * 16 + (lane & 15)) * 8] = pf[i];
      }
      __syncthreads();  // barrier 3: half 1 visible
    }
    f32x4 svA[4], svB[4];
    bf16x8 bFA[4], bFB[4];
    LOAD_SV(svA, h * 16);
    LOAD_BF(bFA, 0);
    #pragma unroll
    for (int ml = 0; ml < 16; ml += 2) {
      LOAD_SV(svB, h * 16 + ml + 1);
      LOAD_BF(bFB, ml + 1);
      COMPUTE_MODE(bFA, svA);
      if (ml + 2 < 16) {
        LOAD_SV(svA, h * 16 + ml + 2);
        LOAD_BF(bFA, ml + 2);
      }
      COMPUTE_MODE(bFB, svB);
    }
  }
#undef LOAD_SV
#undef LOAD_BF
#undef COMPUTE_MODE

  // ---- bias: one K=32 MFMA round (A = sim rows bf16, B = biases) ----
  {
    const bf16x8 bb = *(const bf16x8*)(bb16 + ((long)q * UDIM + strip * 16 + l16) * 8);
    #pragma unroll
    for (int rt = 0; rt < 4; ++rt) {
      const float* sp = sim + (bm + wrow + rt * 16 + l16) * MODES + q * 8;
      const float4 sv0 = *(const float4*)(sp);
      const float4 sv1 = *(const float4*)(sp + 4);
      bf16x8 sF;
      sF[0] = (short)f2bf(sv0.x); sF[1] = (short)f2bf(sv0.y);
      sF[2] = (short)f2bf(sv0.z); sF[3] = (short)f2bf(sv0.w);
      sF[4] = (short)f2bf(sv1.x); sF[5] = (short)f2bf(sv1.y);
      sF[6] = (short)f2bf(sv1.z); sF[7] = (short)f2bf(sv1.w);
      acc[rt] = __builtin_amdgcn_mfma_f32_16x16x32_bf16(sF, bb, acc[rt], 0, 0, 0);
    }
  }

  // ---- epilogue: direct store, 1/MODES folded in ----
  #pragma unroll
  for (int rt = 0; rt < 4; ++rt) {
    const long row = bm + wrow + rt * 16 + q * 4;
    #pragma unroll
    for (int r = 0; r < 4; ++r)
      out[(row + r) * UDIM + strip * 16 + l16] = acc[rt][r] * (1.0f / MODES);
  }
}

extern "C" void kernel_launch(void* const* d_in, const int* in_sizes, int n_in,
                              void* d_out, int out_size, void* d_ws, size_t ws_size,
                              hipStream_t stream) {
  const float* key      = (const float*)d_in[0];
  const float* x        = (const float*)d_in[1];
  const float* sens     = (const float*)d_in[2];
  const float* keys_map = (const float*)d_in[3];
  const float* kernels  = (const float*)d_in[4];
  const float* biases   = (const float*)d_in[5];
  float* out = (float*)d_out;

  char* ws = (char*)d_ws;
  float*          sim  = (float*)ws;                          // 2 MB
  float*          simT = (float*)(ws + (2u << 20));           // 2 MB
  unsigned short* kb16 = (unsigned short*)(ws + (4u << 20));  // 1 MB
  unsigned short* bb16 = (unsigned short*)(ws + (5u << 20));  // 8 KB

  prep_all<<<BATCH / 32 + 258, 256, 0, stream>>>(
      key, sens, keys_map, kernels, biases, sim, simT, kb16, bb16);
  gemm_strip<<<dim3(256), 512, 0, stream>>>(x, kb16, bb16, sim, simT, out);
}